// Round 14
// baseline (203.457 us; speedup 1.0000x reference)
//
#include <hip/hip_runtime.h>
#include <math.h>

#define NB 2
#define NL 256
#define DM 512
#define NH 8
#define DQ 64

// ---------------------------------------------------------------------------
// K1: QKV projection GEMM. 32x64 tile, K-tile 32, thread tile 2x4.
// z==1 (k): written TRANSPOSED (b,h,d,t).
// z==2 (v): NOT stored — block immediately computes u = (v+bias) @ Win_h
//           (n-tile == one head, so the whole head dim is in-block; Win_h is
//           32 KB -> L1-resident). Eliminates v buffer + separate u phase.
// ---------------------------------------------------------------------------
__global__ __launch_bounds__(256) void qkv_gemm(
    const float* __restrict__ xq, const float* __restrict__ xk,
    const float* __restrict__ xv,
    const float* __restrict__ Wq, const float* __restrict__ Wk,
    const float* __restrict__ Wv,
    const float* __restrict__ bq, const float* __restrict__ bk,
    const float* __restrict__ bv,
    const float* __restrict__ Wre, const float* __restrict__ Wim,
    float* __restrict__ q, float* __restrict__ kT, float2* __restrict__ u)
{
    int z = blockIdx.z;
    const float* X = (z == 0) ? xq : (z == 1) ? xk : xv;
    const float* W = (z == 0) ? Wq : (z == 1) ? Wk : Wv;
    const float* bias = (z == 0) ? bq : (z == 1) ? bk : bv;

    __shared__ float As[32][33];
    __shared__ float Bs[32][68];

    int tid = threadIdx.x;
    int tx = tid & 15, ty = tid >> 4;
    int m0 = blockIdx.y * 32, n0 = blockIdx.x * 64;

    float acc[2][4] = {};

    for (int k0 = 0; k0 < 512; k0 += 32) {
        {
            int r = tid >> 3, c4 = (tid & 7) * 4;
            const float4 av = *(const float4*)(X + (m0 + r) * 512 + k0 + c4);
            As[c4 + 0][r] = av.x; As[c4 + 1][r] = av.y;
            As[c4 + 2][r] = av.z; As[c4 + 3][r] = av.w;
        }
        {
            int r = tid >> 4, c4 = (tid & 15) * 4;
            float4 b0 = *(const float4*)(W + (k0 + r) * 512 + n0 + c4);
            float4 b1 = *(const float4*)(W + (k0 + r + 16) * 512 + n0 + c4);
            *(float4*)&Bs[r][c4] = b0;
            *(float4*)&Bs[r + 16][c4] = b1;
        }
        __syncthreads();
        #pragma unroll
        for (int kk = 0; kk < 32; kk++) {
            float a0 = As[kk][ty * 2 + 0];
            float a1 = As[kk][ty * 2 + 1];
            float4 bb = *(const float4*)&Bs[kk][tx * 4];
            acc[0][0] += a0 * bb.x; acc[0][1] += a0 * bb.y;
            acc[0][2] += a0 * bb.z; acc[0][3] += a0 * bb.w;
            acc[1][0] += a1 * bb.x; acc[1][1] += a1 * bb.y;
            acc[1][2] += a1 * bb.z; acc[1][3] += a1 * bb.w;
        }
        __syncthreads();
    }

    if (z < 2) {
        float* O = (z == 0) ? q : kT;
        #pragma unroll
        for (int i = 0; i < 2; i++) {
            int m = m0 + ty * 2 + i;
            int b = m >> 8, l = m & 255;
            #pragma unroll
            for (int j = 0; j < 4; j++) {
                int n = n0 + tx * 4 + j;
                int h = n >> 6, d = n & 63;
                float val = acc[i][j] + bias[n];
                if (z == 1)
                    O[((b * NH + h) * DQ + d) * NL + l] = val;   // kT
                else
                    O[((b * NH + h) * NL + l) * DQ + d] = val;
            }
        }
    } else {
        // ---- fused u: stage v-tile (32 rows x 64 d) into Bs, then
        //      u[b,h,l,e] = sum_d v[l][d] * Win[h][d][e]
        int h = blockIdx.x;            // n-tile == head
        int b = m0 >> 8;
        #pragma unroll
        for (int i = 0; i < 2; i++)
            #pragma unroll
            for (int j = 0; j < 4; j++)
                Bs[ty * 2 + i][tx * 4 + j] = acc[i][j] + bias[n0 + tx * 4 + j];
        __syncthreads();

        int r0 = ty * 2, c4 = tx * 4;
        float ur[2][4] = {}, ui[2][4] = {};
        const float* wr = Wre + h * 4096 + c4;
        const float* wi = Wim + h * 4096 + c4;
        #pragma unroll 4
        for (int d = 0; d < 64; d++) {
            float v0 = Bs[r0][d];
            float v1 = Bs[r0 + 1][d];
            float4 wre = *(const float4*)(wr + d * 64);
            float4 wim = *(const float4*)(wi + d * 64);
            ur[0][0] += v0 * wre.x; ur[0][1] += v0 * wre.y;
            ur[0][2] += v0 * wre.z; ur[0][3] += v0 * wre.w;
            ui[0][0] += v0 * wim.x; ui[0][1] += v0 * wim.y;
            ui[0][2] += v0 * wim.z; ui[0][3] += v0 * wim.w;
            ur[1][0] += v1 * wre.x; ur[1][1] += v1 * wre.y;
            ur[1][2] += v1 * wre.z; ur[1][3] += v1 * wre.w;
            ui[1][0] += v1 * wim.x; ui[1][1] += v1 * wim.y;
            ui[1][2] += v1 * wim.z; ui[1][3] += v1 * wim.w;
        }
        #pragma unroll
        for (int i = 0; i < 2; i++) {
            int l = (m0 & 255) + r0 + i;
            float2* up = u + ((size_t)(b * NH + h) * NL + l) * DQ + c4;
            #pragma unroll
            for (int j = 0; j < 4; j++)
                up[j] = make_float2(ur[i][j], ui[i][j]);
        }
    }
}

// ---------------------------------------------------------------------------
// K2: attn softmax, 8 q-rows per block (R12-passed body). grid (32, NH, NB).
// ---------------------------------------------------------------------------
__global__ __launch_bounds__(256) void attn_kernel(
    const float* __restrict__ q, const float* __restrict__ kT,
    const float* __restrict__ mask, float* __restrict__ attn_o)
{
    int h = blockIdx.y, b = blockIdx.z;
    int tid = threadIdx.x;
    int qg = blockIdx.x;
    __shared__ float sp[2608];   // qs[512] | lg[8*260] | redm[8] | reds[8]

    int wv = tid >> 6, lane = tid & 63;
    float* qs   = sp;
    float* lg   = sp + 512;
    float* redm = sp + 512 + 2080;
    float* reds = redm + 8;

    ((float2*)qs)[tid] =
        ((const float2*)(q + ((size_t)(b * NH + h) * NL + qg * 8) * DQ))[tid];
    __syncthreads();

    const float* kp = kT + (size_t)((b * NH + h) * DQ) * NL + tid;
    float acc[8] = {};
    #pragma unroll
    for (int d4 = 0; d4 < 16; d4++) {
        float kv0 = kp[(d4 * 4 + 0) * NL];
        float kv1 = kp[(d4 * 4 + 1) * NL];
        float kv2 = kp[(d4 * 4 + 2) * NL];
        float kv3 = kp[(d4 * 4 + 3) * NL];
        #pragma unroll
        for (int j = 0; j < 8; j++) {
            const float4 qv = *(const float4*)&qs[j * 64 + d4 * 4];
            acc[j] += qv.x * kv0 + qv.y * kv1 + qv.z * kv2 + qv.w * kv3;
        }
    }
    #pragma unroll
    for (int j = 0; j < 8; j++) {
        float mv = mask[(size_t)(b * NL + qg * 8 + j) * NL + tid];
        acc[j] = acc[j] * 0.125f - ((mv == 1.0f) ? INFINITY : mv);
        lg[j * 260 + tid] = acc[j];
    }
    __syncthreads();
    #pragma unroll
    for (int jj = 0; jj < 2; jj++) {
        int j = wv * 2 + jj;
        float v0 = lg[j * 260 + lane],       v1 = lg[j * 260 + 64 + lane];
        float v2 = lg[j * 260 + 128 + lane], v3 = lg[j * 260 + 192 + lane];
        float mx = fmaxf(fmaxf(v0, v1), fmaxf(v2, v3));
        #pragma unroll
        for (int o = 32; o; o >>= 1) mx = fmaxf(mx, __shfl_xor(mx, o, 64));
        float s = __expf(v0 - mx) + __expf(v1 - mx) +
                  __expf(v2 - mx) + __expf(v3 - mx);
        #pragma unroll
        for (int o = 32; o; o >>= 1) s += __shfl_xor(s, o, 64);
        if (lane == 0) { redm[j] = mx; reds[j] = s; }
    }
    __syncthreads();
    #pragma unroll
    for (int j = 0; j < 8; j++) {
        float p = __expf(acc[j] - redm[j]) * __builtin_amdgcn_rcpf(reds[j]);
        attn_o[((size_t)(b * NH + h) * NL + qg * 8 + j) * NL + tid] = p;
    }
}

// ---------------------------------------------------------------------------
// K3: EUNN recurrence — R6 structure (measured best), arithmetic expressed as
// float2 fma chains (identical per-component expressions/order) to let the
// backend form v_pk_fma_f32 (2x-rate packed FP32). modrelu exact form.
// ---------------------------------------------------------------------------
__device__ __forceinline__ float rot_up2(float x) {   // lane i <- lane (i+2)%64
    int v = __builtin_amdgcn_mov_dpp(__float_as_int(x), 0x134, 0xF, 0xF, true);
    v = __builtin_amdgcn_mov_dpp(v, 0x134, 0xF, 0xF, true);
    return __int_as_float(v);
}
__device__ __forceinline__ float rot_dn2(float x) {   // lane i <- lane (i-2)%64
    int v = __builtin_amdgcn_mov_dpp(__float_as_int(x), 0x13C, 0xF, 0xF, true);
    v = __builtin_amdgcn_mov_dpp(v, 0x13C, 0xF, 0xF, true);
    return __int_as_float(v);
}
__device__ __forceinline__ float2 fma2(float s, float2 a, float2 b) {
    return make_float2(fmaf(s, a.x, b.x), fmaf(s, a.y, b.y));
}
__device__ __forceinline__ float2 mul2(float s, float2 a) {
    return make_float2(s * a.x, s * a.y);
}
__device__ __forceinline__ float2 rot90(float2 a) {   // i*a
    return make_float2(-a.y, a.x);
}

__global__ __launch_bounds__(256) void rnn_kernel(
    const float* __restrict__ attn_f, const float2* __restrict__ u,
    const float* __restrict__ theta, const float* __restrict__ phi,
    const float* __restrict__ rnn_bias, float* __restrict__ rnn_out)
{
    int tid = threadIdx.x;
    int wv = tid >> 6;
    int lane = tid & 63;
    int par = lane & 1;
    int p = lane >> 1;                          // 0..31
    int rec = blockIdx.x * 8 + wv * 2 + par;    // 0..4095
    int qi = rec & 255, h = (rec >> 8) & 7, b = rec >> 11;

    const float* tb = theta + h * 64;
    const float* pb = phi + h * 64;

    float th0 = tb[p], ph0 = pb[p];
    float c0 = cosf(th0), s0 = sinf(th0);
    float cp0 = cosf(ph0), sp0 = sinf(ph0);
    float W0ar = -s0 * cp0, W0ai = -s0 * sp0;
    float W0br =  s0 * cp0, W0bi = -s0 * sp0;

    float th1 = tb[32 + p], ph1 = pb[32 + p];
    float c1 = cosf(th1), s1 = sinf(th1);
    float W1ar = -s1 * cosf(ph1), W1ai = -s1 * sinf(ph1);

    int pm = (p + 31) & 31;
    float th1m = tb[32 + pm], ph1m = pb[32 + pm];
    float c1m = cosf(th1m), s1m = sinf(th1m);
    float W1br = s1m * cosf(ph1m), W1bi = -s1m * sinf(ph1m);

    float bias0 = rnn_bias[h * 64 + 2 * p];
    float bias1 = rnn_bias[h * 64 + 2 * p + 1];

    __shared__ float arow[8 * 256];
    {
        const float4* ap = (const float4*)(attn_f + (size_t)blockIdx.x * 8 * 256);
        ((float4*)arow)[tid] = ap[tid];
        ((float4*)arow)[tid + 256] = ap[tid + 256];
    }
    __syncthreads();
    const float* arc = arow + (wv * 2 + par) * 256;

    const float4* up4 = (const float4*)(u + (size_t)((b * NH + h) * NL) * DQ) + p;

    float2 e0 = make_float2(0.f, 0.f), e1 = make_float2(0.f, 0.f);
    #pragma unroll 8
    for (int t = 0; t < 256; t++) {
        float4 uu = up4[t * 32];
        float a_t = arc[t];

        // stage 0 (in-lane): na = c0*e0 + W0a⊗e1 ; nb = c0*e1 + W0b⊗e0
        float2 na = fma2(c0, e0, fma2(W0ar, e1, mul2(W0ai, rot90(e1))));
        float2 nb = fma2(c0, e1, fma2(W0br, e0, mul2(W0bi, rot90(e0))));

        // neighbor exchange via DPP (pure VALU)
        float2 f1 = make_float2(rot_up2(na.x), rot_up2(na.y));
        float2 f2 = make_float2(rot_dn2(nb.x), rot_dn2(nb.y));

        // stage 1 + input
        float2 z1 = fma2(a_t, make_float2(uu.z, uu.w),
                     fma2(c1, nb, fma2(W1ar, f1, mul2(W1ai, rot90(f1)))));
        float2 z0 = fma2(a_t, make_float2(uu.x, uu.y),
                     fma2(c1m, na, fma2(W1br, f2, mul2(W1bi, rot90(f2)))));

        // modrelu — exact reference form (R7 lesson)
        float mm0 = z0.x * z0.x + z0.y * z0.y;
        float m0 = __builtin_amdgcn_sqrtf(mm0);
        float sc0 = fmaxf(m0 + bias0, 0.f) * __builtin_amdgcn_rcpf(m0 + 1e-5f);
        e0 = mul2(sc0, z0);

        float mm1 = z1.x * z1.x + z1.y * z1.y;
        float m1 = __builtin_amdgcn_sqrtf(mm1);
        float sc1 = fmaxf(m1 + bias1, 0.f) * __builtin_amdgcn_rcpf(m1 + 1e-5f);
        e1 = mul2(sc1, z1);
    }

    *(float2*)&rnn_out[(size_t)(b * NL + qi) * DM + h * DQ + 2 * p] =
        make_float2(e0.x, e1.x);
}

// ---------------------------------------------------------------------------
// K4: output projection. 16x64 tile, K-tile 32 (R3 config). grid (8,32).
// ---------------------------------------------------------------------------
__global__ __launch_bounds__(256) void out_gemm(
    const float* __restrict__ A, const float* __restrict__ W,
    const float* __restrict__ bias, float* __restrict__ C)
{
    __shared__ float As[32][17];
    __shared__ float Bs[32][68];

    int tid = threadIdx.x;
    int tx = tid & 15, ty = tid >> 4;
    int m0 = blockIdx.y * 16, n0 = blockIdx.x * 64;

    float acc[4] = {};

    for (int k0 = 0; k0 < 512; k0 += 32) {
        {
            int r = tid >> 4, c2 = (tid & 15) * 2;
            const float2 av = *(const float2*)(A + (m0 + r) * 512 + k0 + c2);
            As[c2 + 0][r] = av.x; As[c2 + 1][r] = av.y;
        }
        {
            int r = tid >> 4, c4 = (tid & 15) * 4;
            float4 b0 = *(const float4*)(W + (k0 + r) * 512 + n0 + c4);
            float4 b1 = *(const float4*)(W + (k0 + r + 16) * 512 + n0 + c4);
            *(float4*)&Bs[r][c4] = b0;
            *(float4*)&Bs[r + 16][c4] = b1;
        }
        __syncthreads();
        #pragma unroll
        for (int kk = 0; kk < 32; kk++) {
            float a = As[kk][ty];
            float4 bb = *(const float4*)&Bs[kk][tx * 4];
            acc[0] += a * bb.x; acc[1] += a * bb.y;
            acc[2] += a * bb.z; acc[3] += a * bb.w;
        }
        __syncthreads();
    }

    int m = m0 + ty;
    #pragma unroll
    for (int j = 0; j < 4; j++) {
        int n = n0 + tx * 4 + j;
        C[m * 512 + n] = acc[j] + bias[n];
    }
}

// ---------------------------------------------------------------------------
extern "C" void kernel_launch(void* const* d_in, const int* in_sizes, int n_in,
                              void* d_out, int out_size, void* d_ws, size_t ws_size,
                              hipStream_t stream)
{
    const float* x_q  = (const float*)d_in[0];
    const float* x_k  = (const float*)d_in[1];
    const float* x_v  = (const float*)d_in[2];
    const float* mask = (const float*)d_in[3];
    const float* Wq   = (const float*)d_in[4];
    const float* bq   = (const float*)d_in[5];
    const float* Wk   = (const float*)d_in[6];
    const float* bk   = (const float*)d_in[7];
    const float* Wv   = (const float*)d_in[8];
    const float* bv   = (const float*)d_in[9];
    const float* Wo   = (const float*)d_in[10];
    const float* bo   = (const float*)d_in[11];
    const float* theta= (const float*)d_in[12];
    const float* phi  = (const float*)d_in[13];
    const float* Wre  = (const float*)d_in[14];
    const float* Wim  = (const float*)d_in[15];
    const float* rb   = (const float*)d_in[16];

    float* ws = (float*)d_ws;
    float*  q_ws    = ws;                       // 262144 f
    float*  kT_ws   = ws + 262144;              // 262144 f (b,h,d,t)
    float2* u_ws    = (float2*)(ws + 524288);   // 262144 float2
    float*  rnn_o   = ws + 1048576;             // 262144 f

    float* out_o  = (float*)d_out;              // (2,256,512)
    float* attn_o = out_o + NB * NL * DM;       // (2,8,256,256)

    qkv_gemm<<<dim3(8, 16, 3), 256, 0, stream>>>(
        x_q, x_k, x_v, Wq, Wk, Wv, bq, bk, bv, Wre, Wim,
        q_ws, kT_ws, u_ws);

    attn_kernel<<<dim3(32, NH, NB), 256, 0, stream>>>(
        q_ws, kT_ws, mask, attn_o);

    rnn_kernel<<<dim3(512), 256, 0, stream>>>(
        attn_o, u_ws, theta, phi, rb, rnn_o);

    out_gemm<<<dim3(8, 32), 256, 0, stream>>>(rnn_o, Wo, bo, out_o);
}

// Round 15
// 197.703 us; speedup vs baseline: 1.0291x; 1.0291x over previous
//
#include <hip/hip_runtime.h>
#include <math.h>

#define NB 2
#define NL 256
#define DM 512
#define NH 8
#define DQ 64

// ---------------------------------------------------------------------------
// K1: QKV projection GEMM (R14-passed). 32x64 tile, K-tile 32, thread 2x4.
// z==1 (k): written TRANSPOSED (b,h,d,t).
// z==2 (v): not stored — block computes u = (v+bias) @ Win_h in-place.
// ---------------------------------------------------------------------------
__global__ __launch_bounds__(256) void qkv_gemm(
    const float* __restrict__ xq, const float* __restrict__ xk,
    const float* __restrict__ xv,
    const float* __restrict__ Wq, const float* __restrict__ Wk,
    const float* __restrict__ Wv,
    const float* __restrict__ bq, const float* __restrict__ bk,
    const float* __restrict__ bv,
    const float* __restrict__ Wre, const float* __restrict__ Wim,
    float* __restrict__ q, float* __restrict__ kT, float2* __restrict__ u)
{
    int z = blockIdx.z;
    const float* X = (z == 0) ? xq : (z == 1) ? xk : xv;
    const float* W = (z == 0) ? Wq : (z == 1) ? Wk : Wv;
    const float* bias = (z == 0) ? bq : (z == 1) ? bk : bv;

    __shared__ float As[32][33];
    __shared__ float Bs[32][68];

    int tid = threadIdx.x;
    int tx = tid & 15, ty = tid >> 4;
    int m0 = blockIdx.y * 32, n0 = blockIdx.x * 64;

    float acc[2][4] = {};

    for (int k0 = 0; k0 < 512; k0 += 32) {
        {
            int r = tid >> 3, c4 = (tid & 7) * 4;
            const float4 av = *(const float4*)(X + (m0 + r) * 512 + k0 + c4);
            As[c4 + 0][r] = av.x; As[c4 + 1][r] = av.y;
            As[c4 + 2][r] = av.z; As[c4 + 3][r] = av.w;
        }
        {
            int r = tid >> 4, c4 = (tid & 15) * 4;
            float4 b0 = *(const float4*)(W + (k0 + r) * 512 + n0 + c4);
            float4 b1 = *(const float4*)(W + (k0 + r + 16) * 512 + n0 + c4);
            *(float4*)&Bs[r][c4] = b0;
            *(float4*)&Bs[r + 16][c4] = b1;
        }
        __syncthreads();
        #pragma unroll
        for (int kk = 0; kk < 32; kk++) {
            float a0 = As[kk][ty * 2 + 0];
            float a1 = As[kk][ty * 2 + 1];
            float4 bb = *(const float4*)&Bs[kk][tx * 4];
            acc[0][0] += a0 * bb.x; acc[0][1] += a0 * bb.y;
            acc[0][2] += a0 * bb.z; acc[0][3] += a0 * bb.w;
            acc[1][0] += a1 * bb.x; acc[1][1] += a1 * bb.y;
            acc[1][2] += a1 * bb.z; acc[1][3] += a1 * bb.w;
        }
        __syncthreads();
    }

    if (z < 2) {
        float* O = (z == 0) ? q : kT;
        #pragma unroll
        for (int i = 0; i < 2; i++) {
            int m = m0 + ty * 2 + i;
            int b = m >> 8, l = m & 255;
            #pragma unroll
            for (int j = 0; j < 4; j++) {
                int n = n0 + tx * 4 + j;
                int h = n >> 6, d = n & 63;
                float val = acc[i][j] + bias[n];
                if (z == 1)
                    O[((b * NH + h) * DQ + d) * NL + l] = val;   // kT
                else
                    O[((b * NH + h) * NL + l) * DQ + d] = val;
            }
        }
    } else {
        int h = blockIdx.x;            // n-tile == head
        int b = m0 >> 8;
        #pragma unroll
        for (int i = 0; i < 2; i++)
            #pragma unroll
            for (int j = 0; j < 4; j++)
                Bs[ty * 2 + i][tx * 4 + j] = acc[i][j] + bias[n0 + tx * 4 + j];
        __syncthreads();

        int r0 = ty * 2, c4 = tx * 4;
        float ur[2][4] = {}, ui[2][4] = {};
        const float* wr = Wre + h * 4096 + c4;
        const float* wi = Wim + h * 4096 + c4;
        #pragma unroll 4
        for (int d = 0; d < 64; d++) {
            float v0 = Bs[r0][d];
            float v1 = Bs[r0 + 1][d];
            float4 wre = *(const float4*)(wr + d * 64);
            float4 wim = *(const float4*)(wi + d * 64);
            ur[0][0] += v0 * wre.x; ur[0][1] += v0 * wre.y;
            ur[0][2] += v0 * wre.z; ur[0][3] += v0 * wre.w;
            ui[0][0] += v0 * wim.x; ui[0][1] += v0 * wim.y;
            ui[0][2] += v0 * wim.z; ui[0][3] += v0 * wim.w;
            ur[1][0] += v1 * wre.x; ur[1][1] += v1 * wre.y;
            ur[1][2] += v1 * wre.z; ur[1][3] += v1 * wre.w;
            ui[1][0] += v1 * wim.x; ui[1][1] += v1 * wim.y;
            ui[1][2] += v1 * wim.z; ui[1][3] += v1 * wim.w;
        }
        #pragma unroll
        for (int i = 0; i < 2; i++) {
            int l = (m0 & 255) + r0 + i;
            float2* up = u + ((size_t)(b * NH + h) * NL + l) * DQ + c4;
            #pragma unroll
            for (int j = 0; j < 4; j++)
                up[j] = make_float2(ur[i][j], ui[i][j]);
        }
    }
}

// ---------------------------------------------------------------------------
// K2: attn softmax (R12 body, as prologue) + EUNN recurrence (R12 scalar body,
// measured best 64 us). Block blockIdx handles recs blockIdx*8..+7 — one
// (b,h), q-rows qg*8..+7 — exactly one R12 attn block's output, so the attn
// rows are computed here, written to attn_o (output 1) AND kept in LDS for
// the recurrence. One dispatch + one global round-trip removed.
// ---------------------------------------------------------------------------
__device__ __forceinline__ float rot_up2(float x) {   // lane i <- lane (i+2)%64
    int v = __builtin_amdgcn_mov_dpp(__float_as_int(x), 0x134, 0xF, 0xF, true);
    v = __builtin_amdgcn_mov_dpp(v, 0x134, 0xF, 0xF, true);
    return __int_as_float(v);
}
__device__ __forceinline__ float rot_dn2(float x) {   // lane i <- lane (i-2)%64
    int v = __builtin_amdgcn_mov_dpp(__float_as_int(x), 0x13C, 0xF, 0xF, true);
    v = __builtin_amdgcn_mov_dpp(v, 0x13C, 0xF, 0xF, true);
    return __int_as_float(v);
}

__global__ __launch_bounds__(256) void rnn_kernel(
    const float* __restrict__ q, const float* __restrict__ kT,
    const float* __restrict__ mask, float* __restrict__ attn_o,
    const float2* __restrict__ u,
    const float* __restrict__ theta, const float* __restrict__ phi,
    const float* __restrict__ rnn_bias, float* __restrict__ rnn_out)
{
    int tid = threadIdx.x;
    int wv = tid >> 6;
    int lane = tid & 63;

    // block -> (b, h, qg); recs = blockIdx*8..+7, qi = qg*8 + j
    int qg = blockIdx.x & 31;
    int h  = (blockIdx.x >> 5) & 7;
    int b  = blockIdx.x >> 8;

    __shared__ float sp[2608];       // qs[512] | lg[8*260] | redm[8] | reds[8]
    __shared__ float arow[8 * 256];  // attn rows for this block's 8 recs

    // ================= attn prologue (R12 body) =================
    {
        float* qs   = sp;
        float* lg   = sp + 512;
        float* redm = sp + 512 + 2080;
        float* reds = redm + 8;

        ((float2*)qs)[tid] =
            ((const float2*)(q + ((size_t)(b * NH + h) * NL + qg * 8) * DQ))[tid];
        __syncthreads();

        const float* kp = kT + (size_t)((b * NH + h) * DQ) * NL + tid;
        float acc[8] = {};
        #pragma unroll
        for (int d4 = 0; d4 < 16; d4++) {
            float kv0 = kp[(d4 * 4 + 0) * NL];
            float kv1 = kp[(d4 * 4 + 1) * NL];
            float kv2 = kp[(d4 * 4 + 2) * NL];
            float kv3 = kp[(d4 * 4 + 3) * NL];
            #pragma unroll
            for (int j = 0; j < 8; j++) {
                const float4 qv = *(const float4*)&qs[j * 64 + d4 * 4];
                acc[j] += qv.x * kv0 + qv.y * kv1 + qv.z * kv2 + qv.w * kv3;
            }
        }
        #pragma unroll
        for (int j = 0; j < 8; j++) {
            float mv = mask[(size_t)(b * NL + qg * 8 + j) * NL + tid];
            acc[j] = acc[j] * 0.125f - ((mv == 1.0f) ? INFINITY : mv);
            lg[j * 260 + tid] = acc[j];
        }
        __syncthreads();
        #pragma unroll
        for (int jj = 0; jj < 2; jj++) {
            int j = wv * 2 + jj;
            float v0 = lg[j * 260 + lane],       v1 = lg[j * 260 + 64 + lane];
            float v2 = lg[j * 260 + 128 + lane], v3 = lg[j * 260 + 192 + lane];
            float mx = fmaxf(fmaxf(v0, v1), fmaxf(v2, v3));
            #pragma unroll
            for (int o = 32; o; o >>= 1) mx = fmaxf(mx, __shfl_xor(mx, o, 64));
            float s = __expf(v0 - mx) + __expf(v1 - mx) +
                      __expf(v2 - mx) + __expf(v3 - mx);
            #pragma unroll
            for (int o = 32; o; o >>= 1) s += __shfl_xor(s, o, 64);
            if (lane == 0) { redm[j] = mx; reds[j] = s; }
        }
        __syncthreads();
        #pragma unroll
        for (int j = 0; j < 8; j++) {
            float p = __expf(acc[j] - redm[j]) * __builtin_amdgcn_rcpf(reds[j]);
            attn_o[((size_t)(b * NH + h) * NL + qg * 8 + j) * NL + tid] = p;
            arow[j * 256 + tid] = p;
        }
        __syncthreads();
    }

    // ================= EUNN recurrence (R12 scalar body) =================
    int par = lane & 1;
    int p = lane >> 1;                          // 0..31
    int rec = blockIdx.x * 8 + wv * 2 + par;
    int qi = rec & 255;

    const float* tb = theta + h * 64;
    const float* pb = phi + h * 64;

    float th0 = tb[p], ph0 = pb[p];
    float c0 = cosf(th0), s0 = sinf(th0);
    float cp0 = cosf(ph0), sp0 = sinf(ph0);
    float W0ar = -s0 * cp0, W0ai = -s0 * sp0;
    float W0br =  s0 * cp0, W0bi = -s0 * sp0;

    float th1 = tb[32 + p], ph1 = pb[32 + p];
    float c1 = cosf(th1), s1 = sinf(th1);
    float W1ar = -s1 * cosf(ph1), W1ai = -s1 * sinf(ph1);

    int pm = (p + 31) & 31;
    float th1m = tb[32 + pm], ph1m = pb[32 + pm];
    float c1m = cosf(th1m), s1m = sinf(th1m);
    float W1br = s1m * cosf(ph1m), W1bi = -s1m * sinf(ph1m);

    float bias0 = rnn_bias[h * 64 + 2 * p];
    float bias1 = rnn_bias[h * 64 + 2 * p + 1];

    const float* arc = arow + (wv * 2 + par) * 256;
    const float4* up4 = (const float4*)(u + (size_t)((b * NH + h) * NL) * DQ) + p;

    float e0r = 0.f, e0i = 0.f, e1r = 0.f, e1i = 0.f;
    #pragma unroll 8
    for (int t = 0; t < 256; t++) {
        float4 uu = up4[t * 32];
        float a_t = arc[t];

        float na_r = c0 * e0r + (W0ar * e1r - W0ai * e1i);
        float na_i = c0 * e0i + (W0ar * e1i + W0ai * e1r);
        float nb_r = c0 * e1r + (W0br * e0r - W0bi * e0i);
        float nb_i = c0 * e1i + (W0br * e0i + W0bi * e0r);

        float f1r = rot_up2(na_r), f1i = rot_up2(na_i);
        float f2r = rot_dn2(nb_r), f2i = rot_dn2(nb_i);

        float z1r = c1 * nb_r + (W1ar * f1r - W1ai * f1i);
        float z1i = c1 * nb_i + (W1ar * f1i + W1ai * f1r);
        float z0r = c1m * na_r + (W1br * f2r - W1bi * f2i);
        float z0i = c1m * na_i + (W1br * f2i + W1bi * f2r);

        z0r += a_t * uu.x; z0i += a_t * uu.y;
        z1r += a_t * uu.z; z1i += a_t * uu.w;

        // modrelu — exact reference form (R7 lesson: no rsqrt fold)
        float mm0 = z0r * z0r + z0i * z0i;
        float m0 = __builtin_amdgcn_sqrtf(mm0);
        float sc0 = fmaxf(m0 + bias0, 0.f) * __builtin_amdgcn_rcpf(m0 + 1e-5f);
        e0r = z0r * sc0; e0i = z0i * sc0;

        float mm1 = z1r * z1r + z1i * z1i;
        float m1 = __builtin_amdgcn_sqrtf(mm1);
        float sc1 = fmaxf(m1 + bias1, 0.f) * __builtin_amdgcn_rcpf(m1 + 1e-5f);
        e1r = z1r * sc1; e1i = z1i * sc1;
    }

    float2 o = make_float2(e0r, e1r);
    *(float2*)&rnn_out[(size_t)(b * NL + qi) * DM + h * DQ + 2 * p] = o;
}

// ---------------------------------------------------------------------------
// K3: output projection. 16x64 tile, K-tile 32 (R12 config). grid (8,32).
// ---------------------------------------------------------------------------
__global__ __launch_bounds__(256) void out_gemm(
    const float* __restrict__ A, const float* __restrict__ W,
    const float* __restrict__ bias, float* __restrict__ C)
{
    __shared__ float As[32][17];
    __shared__ float Bs[32][68];

    int tid = threadIdx.x;
    int tx = tid & 15, ty = tid >> 4;
    int m0 = blockIdx.y * 16, n0 = blockIdx.x * 64;

    float acc[4] = {};

    for (int k0 = 0; k0 < 512; k0 += 32) {
        {
            int r = tid >> 4, c2 = (tid & 15) * 2;
            const float2 av = *(const float2*)(A + (m0 + r) * 512 + k0 + c2);
            As[c2 + 0][r] = av.x; As[c2 + 1][r] = av.y;
        }
        {
            int r = tid >> 4, c4 = (tid & 15) * 4;
            float4 b0 = *(const float4*)(W + (k0 + r) * 512 + n0 + c4);
            float4 b1 = *(const float4*)(W + (k0 + r + 16) * 512 + n0 + c4);
            *(float4*)&Bs[r][c4] = b0;
            *(float4*)&Bs[r + 16][c4] = b1;
        }
        __syncthreads();
        #pragma unroll
        for (int kk = 0; kk < 32; kk++) {
            float a = As[kk][ty];
            float4 bb = *(const float4*)&Bs[kk][tx * 4];
            acc[0] += a * bb.x; acc[1] += a * bb.y;
            acc[2] += a * bb.z; acc[3] += a * bb.w;
        }
        __syncthreads();
    }

    int m = m0 + ty;
    #pragma unroll
    for (int j = 0; j < 4; j++) {
        int n = n0 + tx * 4 + j;
        C[m * 512 + n] = acc[j] + bias[n];
    }
}

// ---------------------------------------------------------------------------
extern "C" void kernel_launch(void* const* d_in, const int* in_sizes, int n_in,
                              void* d_out, int out_size, void* d_ws, size_t ws_size,
                              hipStream_t stream)
{
    const float* x_q  = (const float*)d_in[0];
    const float* x_k  = (const float*)d_in[1];
    const float* x_v  = (const float*)d_in[2];
    const float* mask = (const float*)d_in[3];
    const float* Wq   = (const float*)d_in[4];
    const float* bq   = (const float*)d_in[5];
    const float* Wk   = (const float*)d_in[6];
    const float* bk   = (const float*)d_in[7];
    const float* Wv   = (const float*)d_in[8];
    const float* bv   = (const float*)d_in[9];
    const float* Wo   = (const float*)d_in[10];
    const float* bo   = (const float*)d_in[11];
    const float* theta= (const float*)d_in[12];
    const float* phi  = (const float*)d_in[13];
    const float* Wre  = (const float*)d_in[14];
    const float* Wim  = (const float*)d_in[15];
    const float* rb   = (const float*)d_in[16];

    float* ws = (float*)d_ws;
    float*  q_ws    = ws;                       // 262144 f
    float*  kT_ws   = ws + 262144;              // 262144 f (b,h,d,t)
    float2* u_ws    = (float2*)(ws + 524288);   // 262144 float2
    float*  rnn_o   = ws + 1048576;             // 262144 f

    float* out_o  = (float*)d_out;              // (2,256,512)
    float* attn_o = out_o + NB * NL * DM;       // (2,8,256,256)

    qkv_gemm<<<dim3(8, 16, 3), 256, 0, stream>>>(
        x_q, x_k, x_v, Wq, Wk, Wv, bq, bk, bv, Wre, Wim,
        q_ws, kT_ws, u_ws);

    rnn_kernel<<<dim3(512), 256, 0, stream>>>(
        q_ws, kT_ws, mask, attn_o, u_ws, theta, phi, rb, rnn_o);

    out_gemm<<<dim3(8, 32), 256, 0, stream>>>(rnn_o, Wo, bo, out_o);
}

// Round 16
// 193.242 us; speedup vs baseline: 1.0529x; 1.0231x over previous
//
#include <hip/hip_runtime.h>
#include <math.h>

#define NB 2
#define NL 256
#define DM 512
#define NH 8
#define DQ 64

// ---------------------------------------------------------------------------
// K1: QKV projection GEMM (R14/R15-passed mappings) with register
// double-buffered K-loop: tile k0+32 is loaded into registers while tile k0
// is consumed from LDS, so global-load latency is exposed once, not 16x.
// z==1 (k): written TRANSPOSED (b,h,d,t).
// z==2 (v): not stored — block computes u = (v+bias) @ Win_h in-place.
// ---------------------------------------------------------------------------
__global__ __launch_bounds__(256) void qkv_gemm(
    const float* __restrict__ xq, const float* __restrict__ xk,
    const float* __restrict__ xv,
    const float* __restrict__ Wq, const float* __restrict__ Wk,
    const float* __restrict__ Wv,
    const float* __restrict__ bq, const float* __restrict__ bk,
    const float* __restrict__ bv,
    const float* __restrict__ Wre, const float* __restrict__ Wim,
    float* __restrict__ q, float* __restrict__ kT, float2* __restrict__ u)
{
    int z = blockIdx.z;
    const float* X = (z == 0) ? xq : (z == 1) ? xk : xv;
    const float* W = (z == 0) ? Wq : (z == 1) ? Wk : Wv;
    const float* bias = (z == 0) ? bq : (z == 1) ? bk : bv;

    __shared__ float As[32][33];
    __shared__ float Bs[32][68];

    int tid = threadIdx.x;
    int tx = tid & 15, ty = tid >> 4;
    int m0 = blockIdx.y * 32, n0 = blockIdx.x * 64;

    // staging addresses (fixed per thread)
    int ar = tid >> 3, ac4 = (tid & 7) * 4;          // A: row, k-quad
    int br = tid >> 4, bc4 = (tid & 15) * 4;         // B: k-row, n-quad
    const float* Aptr = X + (m0 + ar) * 512 + ac4;
    const float* Bptr0 = W + br * 512 + n0 + bc4;
    const float* Bptr1 = W + (br + 16) * 512 + n0 + bc4;

    float acc[2][4] = {};

    // prologue: load k0 = 0 tiles into registers
    float4 aR = *(const float4*)(Aptr);
    float4 bR0 = *(const float4*)(Bptr0);
    float4 bR1 = *(const float4*)(Bptr1);

    for (int k0 = 0; k0 < 512; k0 += 32) {
        // commit current registers to LDS
        As[ac4 + 0][ar] = aR.x; As[ac4 + 1][ar] = aR.y;
        As[ac4 + 2][ar] = aR.z; As[ac4 + 3][ar] = aR.w;
        *(float4*)&Bs[br][bc4] = bR0;
        *(float4*)&Bs[br + 16][bc4] = bR1;
        __syncthreads();

        // prefetch next tile while computing this one
        if (k0 + 32 < 512) {
            aR  = *(const float4*)(Aptr + k0 + 32);
            bR0 = *(const float4*)(Bptr0 + (k0 + 32) * 512);
            bR1 = *(const float4*)(Bptr1 + (k0 + 32) * 512);
        }

        #pragma unroll
        for (int kk = 0; kk < 32; kk++) {
            float a0 = As[kk][ty * 2 + 0];
            float a1 = As[kk][ty * 2 + 1];
            float4 bb = *(const float4*)&Bs[kk][tx * 4];
            acc[0][0] += a0 * bb.x; acc[0][1] += a0 * bb.y;
            acc[0][2] += a0 * bb.z; acc[0][3] += a0 * bb.w;
            acc[1][0] += a1 * bb.x; acc[1][1] += a1 * bb.y;
            acc[1][2] += a1 * bb.z; acc[1][3] += a1 * bb.w;
        }
        __syncthreads();
    }

    if (z < 2) {
        float* O = (z == 0) ? q : kT;
        #pragma unroll
        for (int i = 0; i < 2; i++) {
            int m = m0 + ty * 2 + i;
            int b = m >> 8, l = m & 255;
            #pragma unroll
            for (int j = 0; j < 4; j++) {
                int n = n0 + tx * 4 + j;
                int h = n >> 6, d = n & 63;
                float val = acc[i][j] + bias[n];
                if (z == 1)
                    O[((b * NH + h) * DQ + d) * NL + l] = val;   // kT
                else
                    O[((b * NH + h) * NL + l) * DQ + d] = val;
            }
        }
    } else {
        int h = blockIdx.x;            // n-tile == head
        int b = m0 >> 8;
        #pragma unroll
        for (int i = 0; i < 2; i++)
            #pragma unroll
            for (int j = 0; j < 4; j++)
                Bs[ty * 2 + i][tx * 4 + j] = acc[i][j] + bias[n0 + tx * 4 + j];
        __syncthreads();

        int r0 = ty * 2, c4 = tx * 4;
        float ur[2][4] = {}, ui[2][4] = {};
        const float* wr = Wre + h * 4096 + c4;
        const float* wi = Wim + h * 4096 + c4;
        #pragma unroll 4
        for (int d = 0; d < 64; d++) {
            float v0 = Bs[r0][d];
            float v1 = Bs[r0 + 1][d];
            float4 wre = *(const float4*)(wr + d * 64);
            float4 wim = *(const float4*)(wi + d * 64);
            ur[0][0] += v0 * wre.x; ur[0][1] += v0 * wre.y;
            ur[0][2] += v0 * wre.z; ur[0][3] += v0 * wre.w;
            ui[0][0] += v0 * wim.x; ui[0][1] += v0 * wim.y;
            ui[0][2] += v0 * wim.z; ui[0][3] += v0 * wim.w;
            ur[1][0] += v1 * wre.x; ur[1][1] += v1 * wre.y;
            ur[1][2] += v1 * wre.z; ur[1][3] += v1 * wre.w;
            ui[1][0] += v1 * wim.x; ui[1][1] += v1 * wim.y;
            ui[1][2] += v1 * wim.z; ui[1][3] += v1 * wim.w;
        }
        #pragma unroll
        for (int i = 0; i < 2; i++) {
            int l = (m0 & 255) + r0 + i;
            float2* up = u + ((size_t)(b * NH + h) * NL + l) * DQ + c4;
            #pragma unroll
            for (int j = 0; j < 4; j++)
                up[j] = make_float2(ur[i][j], ui[i][j]);
        }
    }
}

// ---------------------------------------------------------------------------
// K2: attn softmax prologue + EUNN recurrence (R15-passed, unchanged).
// ---------------------------------------------------------------------------
__device__ __forceinline__ float rot_up2(float x) {   // lane i <- lane (i+2)%64
    int v = __builtin_amdgcn_mov_dpp(__float_as_int(x), 0x134, 0xF, 0xF, true);
    v = __builtin_amdgcn_mov_dpp(v, 0x134, 0xF, 0xF, true);
    return __int_as_float(v);
}
__device__ __forceinline__ float rot_dn2(float x) {   // lane i <- lane (i-2)%64
    int v = __builtin_amdgcn_mov_dpp(__float_as_int(x), 0x13C, 0xF, 0xF, true);
    v = __builtin_amdgcn_mov_dpp(v, 0x13C, 0xF, 0xF, true);
    return __int_as_float(v);
}

__global__ __launch_bounds__(256) void rnn_kernel(
    const float* __restrict__ q, const float* __restrict__ kT,
    const float* __restrict__ mask, float* __restrict__ attn_o,
    const float2* __restrict__ u,
    const float* __restrict__ theta, const float* __restrict__ phi,
    const float* __restrict__ rnn_bias, float* __restrict__ rnn_out)
{
    int tid = threadIdx.x;
    int wv = tid >> 6;
    int lane = tid & 63;

    int qg = blockIdx.x & 31;
    int h  = (blockIdx.x >> 5) & 7;
    int b  = blockIdx.x >> 8;

    __shared__ float sp[2608];       // qs[512] | lg[8*260] | redm[8] | reds[8]
    __shared__ float arow[8 * 256];

    // ================= attn prologue =================
    {
        float* qs   = sp;
        float* lg   = sp + 512;
        float* redm = sp + 512 + 2080;
        float* reds = redm + 8;

        ((float2*)qs)[tid] =
            ((const float2*)(q + ((size_t)(b * NH + h) * NL + qg * 8) * DQ))[tid];
        __syncthreads();

        const float* kp = kT + (size_t)((b * NH + h) * DQ) * NL + tid;
        float acc[8] = {};
        #pragma unroll
        for (int d4 = 0; d4 < 16; d4++) {
            float kv0 = kp[(d4 * 4 + 0) * NL];
            float kv1 = kp[(d4 * 4 + 1) * NL];
            float kv2 = kp[(d4 * 4 + 2) * NL];
            float kv3 = kp[(d4 * 4 + 3) * NL];
            #pragma unroll
            for (int j = 0; j < 8; j++) {
                const float4 qv = *(const float4*)&qs[j * 64 + d4 * 4];
                acc[j] += qv.x * kv0 + qv.y * kv1 + qv.z * kv2 + qv.w * kv3;
            }
        }
        #pragma unroll
        for (int j = 0; j < 8; j++) {
            float mv = mask[(size_t)(b * NL + qg * 8 + j) * NL + tid];
            acc[j] = acc[j] * 0.125f - ((mv == 1.0f) ? INFINITY : mv);
            lg[j * 260 + tid] = acc[j];
        }
        __syncthreads();
        #pragma unroll
        for (int jj = 0; jj < 2; jj++) {
            int j = wv * 2 + jj;
            float v0 = lg[j * 260 + lane],       v1 = lg[j * 260 + 64 + lane];
            float v2 = lg[j * 260 + 128 + lane], v3 = lg[j * 260 + 192 + lane];
            float mx = fmaxf(fmaxf(v0, v1), fmaxf(v2, v3));
            #pragma unroll
            for (int o = 32; o; o >>= 1) mx = fmaxf(mx, __shfl_xor(mx, o, 64));
            float s = __expf(v0 - mx) + __expf(v1 - mx) +
                      __expf(v2 - mx) + __expf(v3 - mx);
            #pragma unroll
            for (int o = 32; o; o >>= 1) s += __shfl_xor(s, o, 64);
            if (lane == 0) { redm[j] = mx; reds[j] = s; }
        }
        __syncthreads();
        #pragma unroll
        for (int j = 0; j < 8; j++) {
            float p = __expf(acc[j] - redm[j]) * __builtin_amdgcn_rcpf(reds[j]);
            attn_o[((size_t)(b * NH + h) * NL + qg * 8 + j) * NL + tid] = p;
            arow[j * 256 + tid] = p;
        }
        __syncthreads();
    }

    // ================= EUNN recurrence =================
    int par = lane & 1;
    int p = lane >> 1;
    int rec = blockIdx.x * 8 + wv * 2 + par;
    int qi = rec & 255;

    const float* tb = theta + h * 64;
    const float* pb = phi + h * 64;

    float th0 = tb[p], ph0 = pb[p];
    float c0 = cosf(th0), s0 = sinf(th0);
    float cp0 = cosf(ph0), sp0 = sinf(ph0);
    float W0ar = -s0 * cp0, W0ai = -s0 * sp0;
    float W0br =  s0 * cp0, W0bi = -s0 * sp0;

    float th1 = tb[32 + p], ph1 = pb[32 + p];
    float c1 = cosf(th1), s1 = sinf(th1);
    float W1ar = -s1 * cosf(ph1), W1ai = -s1 * sinf(ph1);

    int pm = (p + 31) & 31;
    float th1m = tb[32 + pm], ph1m = pb[32 + pm];
    float c1m = cosf(th1m), s1m = sinf(th1m);
    float W1br = s1m * cosf(ph1m), W1bi = -s1m * sinf(ph1m);

    float bias0 = rnn_bias[h * 64 + 2 * p];
    float bias1 = rnn_bias[h * 64 + 2 * p + 1];

    const float* arc = arow + (wv * 2 + par) * 256;
    const float4* up4 = (const float4*)(u + (size_t)((b * NH + h) * NL) * DQ) + p;

    float e0r = 0.f, e0i = 0.f, e1r = 0.f, e1i = 0.f;
    #pragma unroll 8
    for (int t = 0; t < 256; t++) {
        float4 uu = up4[t * 32];
        float a_t = arc[t];

        float na_r = c0 * e0r + (W0ar * e1r - W0ai * e1i);
        float na_i = c0 * e0i + (W0ar * e1i + W0ai * e1r);
        float nb_r = c0 * e1r + (W0br * e0r - W0bi * e0i);
        float nb_i = c0 * e1i + (W0br * e0i + W0bi * e0r);

        float f1r = rot_up2(na_r), f1i = rot_up2(na_i);
        float f2r = rot_dn2(nb_r), f2i = rot_dn2(nb_i);

        float z1r = c1 * nb_r + (W1ar * f1r - W1ai * f1i);
        float z1i = c1 * nb_i + (W1ar * f1i + W1ai * f1r);
        float z0r = c1m * na_r + (W1br * f2r - W1bi * f2i);
        float z0i = c1m * na_i + (W1br * f2i + W1bi * f2r);

        z0r += a_t * uu.x; z0i += a_t * uu.y;
        z1r += a_t * uu.z; z1i += a_t * uu.w;

        // modrelu — exact reference form (R7 lesson: no rsqrt fold)
        float mm0 = z0r * z0r + z0i * z0i;
        float m0 = __builtin_amdgcn_sqrtf(mm0);
        float sc0 = fmaxf(m0 + bias0, 0.f) * __builtin_amdgcn_rcpf(m0 + 1e-5f);
        e0r = z0r * sc0; e0i = z0i * sc0;

        float mm1 = z1r * z1r + z1i * z1i;
        float m1 = __builtin_amdgcn_sqrtf(mm1);
        float sc1 = fmaxf(m1 + bias1, 0.f) * __builtin_amdgcn_rcpf(m1 + 1e-5f);
        e1r = z1r * sc1; e1i = z1i * sc1;
    }

    float2 o = make_float2(e0r, e1r);
    *(float2*)&rnn_out[(size_t)(b * NL + qi) * DM + h * DQ + 2 * p] = o;
}

// ---------------------------------------------------------------------------
// K3: output projection. 16x64 tile, K-tile 32, register double-buffered.
// ---------------------------------------------------------------------------
__global__ __launch_bounds__(256) void out_gemm(
    const float* __restrict__ A, const float* __restrict__ W,
    const float* __restrict__ bias, float* __restrict__ C)
{
    __shared__ float As[32][17];
    __shared__ float Bs[32][68];

    int tid = threadIdx.x;
    int tx = tid & 15, ty = tid >> 4;
    int m0 = blockIdx.y * 16, n0 = blockIdx.x * 64;

    int ar = tid >> 4, ac2 = (tid & 15) * 2;
    int br = tid >> 4, bc4 = (tid & 15) * 4;
    const float* Aptr = A + (m0 + ar) * 512 + ac2;
    const float* Bptr0 = W + br * 512 + n0 + bc4;
    const float* Bptr1 = W + (br + 16) * 512 + n0 + bc4;

    float acc[4] = {};

    float2 aR = *(const float2*)(Aptr);
    float4 bR0 = *(const float4*)(Bptr0);
    float4 bR1 = *(const float4*)(Bptr1);

    for (int k0 = 0; k0 < 512; k0 += 32) {
        As[ac2 + 0][ar] = aR.x; As[ac2 + 1][ar] = aR.y;
        *(float4*)&Bs[br][bc4] = bR0;
        *(float4*)&Bs[br + 16][bc4] = bR1;
        __syncthreads();

        if (k0 + 32 < 512) {
            aR  = *(const float2*)(Aptr + k0 + 32);
            bR0 = *(const float4*)(Bptr0 + (k0 + 32) * 512);
            bR1 = *(const float4*)(Bptr1 + (k0 + 32) * 512);
        }

        #pragma unroll
        for (int kk = 0; kk < 32; kk++) {
            float a = As[kk][ty];
            float4 bb = *(const float4*)&Bs[kk][tx * 4];
            acc[0] += a * bb.x; acc[1] += a * bb.y;
            acc[2] += a * bb.z; acc[3] += a * bb.w;
        }
        __syncthreads();
    }

    int m = m0 + ty;
    #pragma unroll
    for (int j = 0; j < 4; j++) {
        int n = n0 + tx * 4 + j;
        C[m * 512 + n] = acc[j] + bias[n];
    }
}

// ---------------------------------------------------------------------------
extern "C" void kernel_launch(void* const* d_in, const int* in_sizes, int n_in,
                              void* d_out, int out_size, void* d_ws, size_t ws_size,
                              hipStream_t stream)
{
    const float* x_q  = (const float*)d_in[0];
    const float* x_k  = (const float*)d_in[1];
    const float* x_v  = (const float*)d_in[2];
    const float* mask = (const float*)d_in[3];
    const float* Wq   = (const float*)d_in[4];
    const float* bq   = (const float*)d_in[5];
    const float* Wk   = (const float*)d_in[6];
    const float* bk   = (const float*)d_in[7];
    const float* Wv   = (const float*)d_in[8];
    const float* bv   = (const float*)d_in[9];
    const float* Wo   = (const float*)d_in[10];
    const float* bo   = (const float*)d_in[11];
    const float* theta= (const float*)d_in[12];
    const float* phi  = (const float*)d_in[13];
    const float* Wre  = (const float*)d_in[14];
    const float* Wim  = (const float*)d_in[15];
    const float* rb   = (const float*)d_in[16];

    float* ws = (float*)d_ws;
    float*  q_ws    = ws;                       // 262144 f
    float*  kT_ws   = ws + 262144;              // 262144 f (b,h,d,t)
    float2* u_ws    = (float2*)(ws + 524288);   // 262144 float2
    float*  rnn_o   = ws + 1048576;             // 262144 f

    float* out_o  = (float*)d_out;              // (2,256,512)
    float* attn_o = out_o + NB * NL * DM;       // (2,8,256,256)

    qkv_gemm<<<dim3(8, 16, 3), 256, 0, stream>>>(
        x_q, x_k, x_v, Wq, Wk, Wv, bq, bk, bv, Wre, Wim,
        q_ws, kT_ws, u_ws);

    rnn_kernel<<<dim3(512), 256, 0, stream>>>(
        q_ws, kT_ws, mask, attn_o, u_ws, theta, phi, rb, rnn_o);

    out_gemm<<<dim3(8, 32), 256, 0, stream>>>(rnn_o, Wo, bo, out_o);
}

// Round 17
// 186.299 us; speedup vs baseline: 1.0921x; 1.0373x over previous
//
#include <hip/hip_runtime.h>
#include <math.h>

#define NB 2
#define NL 256
#define DM 512
#define NH 8
#define DQ 64

typedef float v2f __attribute__((ext_vector_type(2)));

#if __has_builtin(__builtin_elementwise_fma)
__device__ __forceinline__ v2f fmav(v2f a, v2f b, v2f c) {
    return __builtin_elementwise_fma(a, b, c);
}
#else
__device__ __forceinline__ v2f fmav(v2f a, v2f b, v2f c) {
    v2f r; r.x = fmaf(a.x, b.x, c.x); r.y = fmaf(a.y, b.y, c.y); return r;
}
#endif
__device__ __forceinline__ v2f swapv(v2f a) {
    return __builtin_shufflevector(a, a, 1, 0);
}

// ---------------------------------------------------------------------------
// K1: QKV projection GEMM (R16-passed, unchanged). Register double-buffered.
// z==1 (k): TRANSPOSED (b,h,d,t). z==2 (v): computes u = (v+bias)@Win_h.
// ---------------------------------------------------------------------------
__global__ __launch_bounds__(256) void qkv_gemm(
    const float* __restrict__ xq, const float* __restrict__ xk,
    const float* __restrict__ xv,
    const float* __restrict__ Wq, const float* __restrict__ Wk,
    const float* __restrict__ Wv,
    const float* __restrict__ bq, const float* __restrict__ bk,
    const float* __restrict__ bv,
    const float* __restrict__ Wre, const float* __restrict__ Wim,
    float* __restrict__ q, float* __restrict__ kT, float2* __restrict__ u)
{
    int z = blockIdx.z;
    const float* X = (z == 0) ? xq : (z == 1) ? xk : xv;
    const float* W = (z == 0) ? Wq : (z == 1) ? Wk : Wv;
    const float* bias = (z == 0) ? bq : (z == 1) ? bk : bv;

    __shared__ float As[32][33];
    __shared__ float Bs[32][68];

    int tid = threadIdx.x;
    int tx = tid & 15, ty = tid >> 4;
    int m0 = blockIdx.y * 32, n0 = blockIdx.x * 64;

    int ar = tid >> 3, ac4 = (tid & 7) * 4;
    int br = tid >> 4, bc4 = (tid & 15) * 4;
    const float* Aptr = X + (m0 + ar) * 512 + ac4;
    const float* Bptr0 = W + br * 512 + n0 + bc4;
    const float* Bptr1 = W + (br + 16) * 512 + n0 + bc4;

    float acc[2][4] = {};

    float4 aR = *(const float4*)(Aptr);
    float4 bR0 = *(const float4*)(Bptr0);
    float4 bR1 = *(const float4*)(Bptr1);

    for (int k0 = 0; k0 < 512; k0 += 32) {
        As[ac4 + 0][ar] = aR.x; As[ac4 + 1][ar] = aR.y;
        As[ac4 + 2][ar] = aR.z; As[ac4 + 3][ar] = aR.w;
        *(float4*)&Bs[br][bc4] = bR0;
        *(float4*)&Bs[br + 16][bc4] = bR1;
        __syncthreads();

        if (k0 + 32 < 512) {
            aR  = *(const float4*)(Aptr + k0 + 32);
            bR0 = *(const float4*)(Bptr0 + (k0 + 32) * 512);
            bR1 = *(const float4*)(Bptr1 + (k0 + 32) * 512);
        }

        #pragma unroll
        for (int kk = 0; kk < 32; kk++) {
            float a0 = As[kk][ty * 2 + 0];
            float a1 = As[kk][ty * 2 + 1];
            float4 bb = *(const float4*)&Bs[kk][tx * 4];
            acc[0][0] += a0 * bb.x; acc[0][1] += a0 * bb.y;
            acc[0][2] += a0 * bb.z; acc[0][3] += a0 * bb.w;
            acc[1][0] += a1 * bb.x; acc[1][1] += a1 * bb.y;
            acc[1][2] += a1 * bb.z; acc[1][3] += a1 * bb.w;
        }
        __syncthreads();
    }

    if (z < 2) {
        float* O = (z == 0) ? q : kT;
        #pragma unroll
        for (int i = 0; i < 2; i++) {
            int m = m0 + ty * 2 + i;
            int b = m >> 8, l = m & 255;
            #pragma unroll
            for (int j = 0; j < 4; j++) {
                int n = n0 + tx * 4 + j;
                int h = n >> 6, d = n & 63;
                float val = acc[i][j] + bias[n];
                if (z == 1)
                    O[((b * NH + h) * DQ + d) * NL + l] = val;   // kT
                else
                    O[((b * NH + h) * NL + l) * DQ + d] = val;
            }
        }
    } else {
        int h = blockIdx.x;            // n-tile == head
        int b = m0 >> 8;
        #pragma unroll
        for (int i = 0; i < 2; i++)
            #pragma unroll
            for (int j = 0; j < 4; j++)
                Bs[ty * 2 + i][tx * 4 + j] = acc[i][j] + bias[n0 + tx * 4 + j];
        __syncthreads();

        int r0 = ty * 2, c4 = tx * 4;
        float ur[2][4] = {}, ui[2][4] = {};
        const float* wr = Wre + h * 4096 + c4;
        const float* wi = Wim + h * 4096 + c4;
        #pragma unroll 4
        for (int d = 0; d < 64; d++) {
            float v0 = Bs[r0][d];
            float v1 = Bs[r0 + 1][d];
            float4 wre = *(const float4*)(wr + d * 64);
            float4 wim = *(const float4*)(wi + d * 64);
            ur[0][0] += v0 * wre.x; ur[0][1] += v0 * wre.y;
            ur[0][2] += v0 * wre.z; ur[0][3] += v0 * wre.w;
            ui[0][0] += v0 * wim.x; ui[0][1] += v0 * wim.y;
            ui[0][2] += v0 * wim.z; ui[0][3] += v0 * wim.w;
            ur[1][0] += v1 * wre.x; ur[1][1] += v1 * wre.y;
            ur[1][2] += v1 * wre.z; ur[1][3] += v1 * wre.w;
            ui[1][0] += v1 * wim.x; ui[1][1] += v1 * wim.y;
            ui[1][2] += v1 * wim.z; ui[1][3] += v1 * wim.w;
        }
        #pragma unroll
        for (int i = 0; i < 2; i++) {
            int l = (m0 & 255) + r0 + i;
            float2* up = u + ((size_t)(b * NH + h) * NL + l) * DQ + c4;
            #pragma unroll
            for (int j = 0; j < 4; j++)
                up[j] = make_float2(ur[i][j], ui[i][j]);
        }
    }
}

// ---------------------------------------------------------------------------
// K2: attn softmax prologue (R16-passed) + EUNN recurrence, packed-FP32 form:
// complex math as ext_vector_type(2) fma chains so ISel forms v_pk_fma_f32.
//   W⊗e: z = pk_fma(splat(Wr), e, pk_mul((-Wi,+Wi), swap(e)))
// Same fp32 fma ops as R16's scalar body (only the a_t*u association moved
// innermost — ulp-level noise, not the R7 systematic-inflation class).
// ---------------------------------------------------------------------------
__device__ __forceinline__ float rot_up2(float x) {   // lane i <- lane (i+2)%64
    int v = __builtin_amdgcn_mov_dpp(__float_as_int(x), 0x134, 0xF, 0xF, true);
    v = __builtin_amdgcn_mov_dpp(v, 0x134, 0xF, 0xF, true);
    return __int_as_float(v);
}
__device__ __forceinline__ float rot_dn2(float x) {   // lane i <- lane (i-2)%64
    int v = __builtin_amdgcn_mov_dpp(__float_as_int(x), 0x13C, 0xF, 0xF, true);
    v = __builtin_amdgcn_mov_dpp(v, 0x13C, 0xF, 0xF, true);
    return __int_as_float(v);
}

__global__ __launch_bounds__(256) void rnn_kernel(
    const float* __restrict__ q, const float* __restrict__ kT,
    const float* __restrict__ mask, float* __restrict__ attn_o,
    const float2* __restrict__ u,
    const float* __restrict__ theta, const float* __restrict__ phi,
    const float* __restrict__ rnn_bias, float* __restrict__ rnn_out)
{
    int tid = threadIdx.x;
    int wv = tid >> 6;
    int lane = tid & 63;

    int qg = blockIdx.x & 31;
    int h  = (blockIdx.x >> 5) & 7;
    int b  = blockIdx.x >> 8;

    __shared__ float sp[2608];       // qs[512] | lg[8*260] | redm[8] | reds[8]
    __shared__ float arow[8 * 256];

    // ================= attn prologue (R16-passed) =================
    {
        float* qs   = sp;
        float* lg   = sp + 512;
        float* redm = sp + 512 + 2080;
        float* reds = redm + 8;

        ((float2*)qs)[tid] =
            ((const float2*)(q + ((size_t)(b * NH + h) * NL + qg * 8) * DQ))[tid];
        __syncthreads();

        const float* kp = kT + (size_t)((b * NH + h) * DQ) * NL + tid;
        float acc[8] = {};
        #pragma unroll
        for (int d4 = 0; d4 < 16; d4++) {
            float kv0 = kp[(d4 * 4 + 0) * NL];
            float kv1 = kp[(d4 * 4 + 1) * NL];
            float kv2 = kp[(d4 * 4 + 2) * NL];
            float kv3 = kp[(d4 * 4 + 3) * NL];
            #pragma unroll
            for (int j = 0; j < 8; j++) {
                const float4 qv = *(const float4*)&qs[j * 64 + d4 * 4];
                acc[j] += qv.x * kv0 + qv.y * kv1 + qv.z * kv2 + qv.w * kv3;
            }
        }
        #pragma unroll
        for (int j = 0; j < 8; j++) {
            float mv = mask[(size_t)(b * NL + qg * 8 + j) * NL + tid];
            acc[j] = acc[j] * 0.125f - ((mv == 1.0f) ? INFINITY : mv);
            lg[j * 260 + tid] = acc[j];
        }
        __syncthreads();
        #pragma unroll
        for (int jj = 0; jj < 2; jj++) {
            int j = wv * 2 + jj;
            float v0 = lg[j * 260 + lane],       v1 = lg[j * 260 + 64 + lane];
            float v2 = lg[j * 260 + 128 + lane], v3 = lg[j * 260 + 192 + lane];
            float mx = fmaxf(fmaxf(v0, v1), fmaxf(v2, v3));
            #pragma unroll
            for (int o = 32; o; o >>= 1) mx = fmaxf(mx, __shfl_xor(mx, o, 64));
            float s = __expf(v0 - mx) + __expf(v1 - mx) +
                      __expf(v2 - mx) + __expf(v3 - mx);
            #pragma unroll
            for (int o = 32; o; o >>= 1) s += __shfl_xor(s, o, 64);
            if (lane == 0) { redm[j] = mx; reds[j] = s; }
        }
        __syncthreads();
        #pragma unroll
        for (int j = 0; j < 8; j++) {
            float p = __expf(acc[j] - redm[j]) * __builtin_amdgcn_rcpf(reds[j]);
            attn_o[((size_t)(b * NH + h) * NL + qg * 8 + j) * NL + tid] = p;
            arow[j * 256 + tid] = p;
        }
        __syncthreads();
    }

    // ================= EUNN recurrence (packed-FP32) =================
    int par = lane & 1;
    int p = lane >> 1;
    int rec = blockIdx.x * 8 + wv * 2 + par;
    int qi = rec & 255;

    const float* tb = theta + h * 64;
    const float* pb = phi + h * 64;

    float th0 = tb[p], ph0 = pb[p];
    float c0 = cosf(th0), s0 = sinf(th0);
    float cp0 = cosf(ph0), sp0 = sinf(ph0);
    float W0ar = -s0 * cp0, W0ai = -s0 * sp0;
    float W0br =  s0 * cp0, W0bi = -s0 * sp0;

    float th1 = tb[32 + p], ph1 = pb[32 + p];
    float c1 = cosf(th1), s1 = sinf(th1);
    float W1ar = -s1 * cosf(ph1), W1ai = -s1 * sinf(ph1);

    int pm = (p + 31) & 31;
    float th1m = tb[32 + pm], ph1m = pb[32 + pm];
    float c1m = cosf(th1m), s1m = sinf(th1m);
    float W1br = s1m * cosf(ph1m), W1bi = -s1m * sinf(ph1m);

    float bias0 = rnn_bias[h * 64 + 2 * p];
    float bias1 = rnn_bias[h * 64 + 2 * p + 1];

    // packed per-lane constants
    v2f c0v  = {c0, c0},   c1v  = {c1, c1},   c1mv = {c1m, c1m};
    v2f W0arV = {W0ar, W0ar}, W0aiN = {-W0ai, W0ai};
    v2f W0brV = {W0br, W0br}, W0biN = {-W0bi, W0bi};
    v2f W1arV = {W1ar, W1ar}, W1aiN = {-W1ai, W1ai};
    v2f W1brV = {W1br, W1br}, W1biN = {-W1bi, W1bi};

    const float* arc = arow + (wv * 2 + par) * 256;
    const float4* up4 = (const float4*)(u + (size_t)((b * NH + h) * NL) * DQ) + p;

    v2f e0 = {0.f, 0.f}, e1 = {0.f, 0.f};
    #pragma unroll 8
    for (int t = 0; t < 256; t++) {
        float4 uu = up4[t * 32];
        float a_t = arc[t];
        v2f atv = {a_t, a_t};
        v2f u0 = {uu.x, uu.y}, u1 = {uu.z, uu.w};

        // stage 0: na = c0*e0 + W0a⊗e1 ; nb = c0*e1 + W0b⊗e0
        v2f na = fmav(c0v, e0, fmav(W0arV, e1, W0aiN * swapv(e1)));
        v2f nb = fmav(c0v, e1, fmav(W0brV, e0, W0biN * swapv(e0)));

        // neighbor exchange via DPP (per 32-bit component)
        v2f f1, f2;
        f1.x = rot_up2(na.x); f1.y = rot_up2(na.y);
        f2.x = rot_dn2(nb.x); f2.y = rot_dn2(nb.y);

        // stage 1 + input
        v2f z1 = fmav(c1v, nb, fmav(W1arV, f1, fmav(W1aiN, swapv(f1), atv * u1)));
        v2f z0 = fmav(c1mv, na, fmav(W1brV, f2, fmav(W1biN, swapv(f2), atv * u0)));

        // modrelu — exact reference form (R7 lesson: no rsqrt fold)
        float mm0 = z0.x * z0.x + z0.y * z0.y;
        float m0 = __builtin_amdgcn_sqrtf(mm0);
        float sc0 = fmaxf(m0 + bias0, 0.f) * __builtin_amdgcn_rcpf(m0 + 1e-5f);
        v2f sc0v = {sc0, sc0};
        e0 = z0 * sc0v;

        float mm1 = z1.x * z1.x + z1.y * z1.y;
        float m1 = __builtin_amdgcn_sqrtf(mm1);
        float sc1 = fmaxf(m1 + bias1, 0.f) * __builtin_amdgcn_rcpf(m1 + 1e-5f);
        v2f sc1v = {sc1, sc1};
        e1 = z1 * sc1v;
    }

    float2 o = make_float2(e0.x, e1.x);
    *(float2*)&rnn_out[(size_t)(b * NL + qi) * DM + h * DQ + 2 * p] = o;
}

// ---------------------------------------------------------------------------
// K3: output projection (R16-passed, unchanged). Register double-buffered.
// ---------------------------------------------------------------------------
__global__ __launch_bounds__(256) void out_gemm(
    const float* __restrict__ A, const float* __restrict__ W,
    const float* __restrict__ bias, float* __restrict__ C)
{
    __shared__ float As[32][17];
    __shared__ float Bs[32][68];

    int tid = threadIdx.x;
    int tx = tid & 15, ty = tid >> 4;
    int m0 = blockIdx.y * 16, n0 = blockIdx.x * 64;

    int ar = tid >> 4, ac2 = (tid & 15) * 2;
    int br = tid >> 4, bc4 = (tid & 15) * 4;
    const float* Aptr = A + (m0 + ar) * 512 + ac2;
    const float* Bptr0 = W + br * 512 + n0 + bc4;
    const float* Bptr1 = W + (br + 16) * 512 + n0 + bc4;

    float acc[4] = {};

    float2 aR = *(const float2*)(Aptr);
    float4 bR0 = *(const float4*)(Bptr0);
    float4 bR1 = *(const float4*)(Bptr1);

    for (int k0 = 0; k0 < 512; k0 += 32) {
        As[ac2 + 0][ar] = aR.x; As[ac2 + 1][ar] = aR.y;
        *(float4*)&Bs[br][bc4] = bR0;
        *(float4*)&Bs[br + 16][bc4] = bR1;
        __syncthreads();

        if (k0 + 32 < 512) {
            aR  = *(const float2*)(Aptr + k0 + 32);
            bR0 = *(const float4*)(Bptr0 + (k0 + 32) * 512);
            bR1 = *(const float4*)(Bptr1 + (k0 + 32) * 512);
        }

        #pragma unroll
        for (int kk = 0; kk < 32; kk++) {
            float a = As[kk][ty];
            float4 bb = *(const float4*)&Bs[kk][tx * 4];
            acc[0] += a * bb.x; acc[1] += a * bb.y;
            acc[2] += a * bb.z; acc[3] += a * bb.w;
        }
        __syncthreads();
    }

    int m = m0 + ty;
    #pragma unroll
    for (int j = 0; j < 4; j++) {
        int n = n0 + tx * 4 + j;
        C[m * 512 + n] = acc[j] + bias[n];
    }
}

// ---------------------------------------------------------------------------
extern "C" void kernel_launch(void* const* d_in, const int* in_sizes, int n_in,
                              void* d_out, int out_size, void* d_ws, size_t ws_size,
                              hipStream_t stream)
{
    const float* x_q  = (const float*)d_in[0];
    const float* x_k  = (const float*)d_in[1];
    const float* x_v  = (const float*)d_in[2];
    const float* mask = (const float*)d_in[3];
    const float* Wq   = (const float*)d_in[4];
    const float* bq   = (const float*)d_in[5];
    const float* Wk   = (const float*)d_in[6];
    const float* bk   = (const float*)d_in[7];
    const float* Wv   = (const float*)d_in[8];
    const float* bv   = (const float*)d_in[9];
    const float* Wo   = (const float*)d_in[10];
    const float* bo   = (const float*)d_in[11];
    const float* theta= (const float*)d_in[12];
    const float* phi  = (const float*)d_in[13];
    const float* Wre  = (const float*)d_in[14];
    const float* Wim  = (const float*)d_in[15];
    const float* rb   = (const float*)d_in[16];

    float* ws = (float*)d_ws;
    float*  q_ws    = ws;                       // 262144 f
    float*  kT_ws   = ws + 262144;              // 262144 f (b,h,d,t)
    float2* u_ws    = (float2*)(ws + 524288);   // 262144 float2
    float*  rnn_o   = ws + 1048576;             // 262144 f

    float* out_o  = (float*)d_out;              // (2,256,512)
    float* attn_o = out_o + NB * NL * DM;       // (2,8,256,256)

    qkv_gemm<<<dim3(8, 16, 3), 256, 0, stream>>>(
        x_q, x_k, x_v, Wq, Wk, Wv, bq, bk, bv, Wre, Wim,
        q_ws, kT_ws, u_ws);

    rnn_kernel<<<dim3(512), 256, 0, stream>>>(
        q_ws, kT_ws, mask, attn_o, u_ws, theta, phi, rb, rnn_o);

    out_gemm<<<dim3(8, 32), 256, 0, stream>>>(rnn_o, Wo, bo, out_o);
}